// Round 7
// baseline (278.126 us; speedup 1.0000x reference)
//
#include <hip/hip_runtime.h>
#include <math.h>

#define BB  256
#define TCC 256
#define DD  2048
#define PSTRIDE 2056   // attn partial stride in floats: [m,l,pad..8, acc 2048]

typedef float4 f4;
typedef float __attribute__((ext_vector_type(4))) fv4;

// ---------------------------------------------------------------------------
// Kernel A: hw = h_dec @ W  (f32), split-K into 4 partials stored in d_ws.
// grid (32 e-tiles, 4 b-tiles, 4 k-splits), 256 threads.  (unchanged)
// ---------------------------------------------------------------------------
__global__ __launch_bounds__(256) void hw_gemm_partial(
    const float* __restrict__ h,     // [B][D]
    const float* __restrict__ W,     // [D][D]
    float* __restrict__ part)        // [4][B][D]
{
    __shared__ float hs[32][68];     // [d][b] transposed
    __shared__ float wsm[32][64];    // [d][e]

    const int tid = threadIdx.x;
    const int e0 = blockIdx.x * 64;
    const int b0 = blockIdx.y * 64;
    const int z  = blockIdx.z;

    float acc[4][4];
    #pragma unroll
    for (int i = 0; i < 4; i++)
        #pragma unroll
        for (int j = 0; j < 4; j++) acc[i][j] = 0.f;

    const int ie = tid & 15;
    const int ib = tid >> 4;

    const int hr = tid >> 2;
    const int hc = (tid & 3) * 8;
    const int wr = tid >> 3;
    const int wc = (tid & 7) * 8;

    for (int d0 = z * 512; d0 < z * 512 + 512; d0 += 32) {
        f4 ha = *(const f4*)&h[(size_t)(b0 + hr) * DD + d0 + hc];
        f4 hb = *(const f4*)&h[(size_t)(b0 + hr) * DD + d0 + hc + 4];
        hs[hc + 0][hr] = ha.x; hs[hc + 1][hr] = ha.y;
        hs[hc + 2][hr] = ha.z; hs[hc + 3][hr] = ha.w;
        hs[hc + 4][hr] = hb.x; hs[hc + 5][hr] = hb.y;
        hs[hc + 6][hr] = hb.z; hs[hc + 7][hr] = hb.w;
        f4 wa = *(const f4*)&W[(size_t)(d0 + wr) * DD + e0 + wc];
        f4 wb = *(const f4*)&W[(size_t)(d0 + wr) * DD + e0 + wc + 4];
        *(f4*)&wsm[wr][wc]     = wa;
        *(f4*)&wsm[wr][wc + 4] = wb;
        __syncthreads();

        #pragma unroll
        for (int dd = 0; dd < 32; dd++) {
            f4 hv = *(const f4*)&hs[dd][ib * 4];
            f4 wv = *(const f4*)&wsm[dd][ie * 4];
            float hvv[4] = {hv.x, hv.y, hv.z, hv.w};
            float wvv[4] = {wv.x, wv.y, wv.z, wv.w};
            #pragma unroll
            for (int i = 0; i < 4; i++)
                #pragma unroll
                for (int j = 0; j < 4; j++)
                    acc[i][j] += hvv[i] * wvv[j];
        }
        __syncthreads();
    }

    #pragma unroll
    for (int i = 0; i < 4; i++) {
        f4 v = make_float4(acc[i][0], acc[i][1], acc[i][2], acc[i][3]);
        *(f4*)&part[((size_t)z * BB + b0 + ib * 4 + i) * DD + e0 + ie * 4] = v;
    }
}

// ---------------------------------------------------------------------------
// Kernel B v6: block-lockstep attention + copy with DEPTH-3 rotating
// register prefetch (statically named buffers -> no scratch, no spill).
// grid (4 chunks, B), 256 threads (4 waves). Block handles timesteps
// [64c, 64c+64); each thread owns 8 channels (acc + hw in registers).
// One barrier per timestep (double-buffered wred). Partials -> d_ws.
// ---------------------------------------------------------------------------
__global__ __launch_bounds__(256, 4) void attn_part6(
    const float* __restrict__ prev,    // [B][TC][D]
    const unsigned char* __restrict__ maskb,
    const float* __restrict__ part,    // [4][B][D] hw gemm partials
    float* __restrict__ apart,         // [B][4][PSTRIDE] attn partials
    float* __restrict__ out)           // [B*D ctx | B*(TC+1)*D new_prev]
{
    __shared__ float wred[2][4];

    const int c   = blockIdx.x;
    const int b   = blockIdx.y;
    const int tid = threadIdx.x;
    const int w   = tid >> 6;
    const int ln  = tid & 63;
    const int t0  = c * 64;
    const int k8  = tid * 8;

    // hw for this thread's 8 channels (sum the 4 split-K gemm partials)
    fv4 hw0, hw1;
    {
        const float* p0 = part + (size_t)b * DD + k8;
        hw0 = *(const fv4*)p0;
        hw1 = *(const fv4*)(p0 + 4);
        #pragma unroll
        for (int z = 1; z < 4; ++z) {
            const float* pz = part + ((size_t)z * BB + b) * DD + k8;
            hw0 += *(const fv4*)pz;
            hw1 += *(const fv4*)(pz + 4);
        }
    }

    // mask dtype-layout detection: bool bytes -> nonzero bytes at k%4!=0
    int nzc = 0;
    #pragma unroll
    for (int k = 1; k < 64; k++)
        if ((k & 3) != 0) nzc += (maskb[k] != 0);
    const bool boolLayout = (nzc > 0);
    const int* maski = (const int*)maskb;

    const float* pb = prev + (size_t)b * TCC * DD + k8;
    float* cp = out + (size_t)BB * DD + (size_t)b * (TCC + 1) * DD + k8;

    fv4 a0 = (fv4)(0.f), a1 = (fv4)(0.f);
    float m = -INFINITY, l = 0.f;

    fv4 P0a, P0b, P1a, P1b, P2a, P2b;

    // preload t0, t0+1, t0+2
    {
        const float* s0 = pb + (size_t)t0 * DD;
        P0a = __builtin_nontemporal_load((const fv4*)s0);
        P0b = __builtin_nontemporal_load((const fv4*)(s0 + 4));
        const float* s1 = s0 + DD;
        P1a = __builtin_nontemporal_load((const fv4*)s1);
        P1b = __builtin_nontemporal_load((const fv4*)(s1 + 4));
        const float* s2 = s1 + DD;
        P2a = __builtin_nontemporal_load((const fv4*)s2);
        P2b = __builtin_nontemporal_load((const fv4*)(s2 + 4));
    }

    #define STEP(Pa, Pb, I)                                                    \
    {                                                                          \
        const int i = (I);                                                     \
        const int t = t0 + i;                                                  \
        fv4 ca = Pa, cb = Pb;                                                  \
        int tn = t + 3; if (tn > t0 + 63) tn = t0 + 63;                        \
        const float* sn = pb + (size_t)tn * DD;                                \
        Pa = __builtin_nontemporal_load((const fv4*)sn);                       \
        Pb = __builtin_nontemporal_load((const fv4*)(sn + 4));                 \
        if (i < 64) {                                                          \
            float* d = cp + (size_t)t * DD;                                    \
            *(fv4*)d       = ca;                                               \
            *(fv4*)(d + 4) = cb;                                               \
            float p = ca.x * hw0.x + ca.y * hw0.y + ca.z * hw0.z               \
                    + ca.w * hw0.w + cb.x * hw1.x + cb.y * hw1.y               \
                    + cb.z * hw1.z + cb.w * hw1.w;                             \
            _Pragma("unroll")                                                  \
            for (int off = 32; off; off >>= 1) p += __shfl_xor(p, off, 64);    \
            if (ln == 0) wred[i & 1][w] = p;                                   \
            __syncthreads();                                                   \
            const float e = wred[i & 1][0] + wred[i & 1][1]                    \
                          + wred[i & 1][2] + wred[i & 1][3];                   \
            const bool mk = boolLayout ? (maskb[(size_t)b * TCC + t] != 0)     \
                                       : (maski[(size_t)b * TCC + t] != 0);    \
            if (mk) {                                                          \
                if (e > m) {                                                   \
                    const float s = __expf(m - e);                             \
                    l *= s; a0 *= s; a1 *= s;                                  \
                    m = e;                                                     \
                }                                                              \
                const float wgt = __expf(e - m);                               \
                l += wgt;                                                      \
                a0 += wgt * ca;                                                \
                a1 += wgt * cb;                                                \
            }                                                                  \
        }                                                                      \
    }

    #pragma unroll 1
    for (int kk = 0; kk < 66; kk += 3) {
        STEP(P0a, P0b, kk + 0);
        STEP(P1a, P1b, kk + 1);
        STEP(P2a, P2b, kk + 2);
    }
    #undef STEP

    // write block partial: [m, l, acc 2048]
    float* bp = apart + ((size_t)b * 4 + c) * PSTRIDE;
    if (tid == 0) { bp[0] = m; bp[1] = l; }
    *(fv4*)(bp + 8 + k8)     = a0;
    *(fv4*)(bp + 8 + k8 + 4) = a1;
}

// ---------------------------------------------------------------------------
// Kernel C: merge the 4 chunk partials per batch row -> ctx; append h_dec.
// grid (B), 256 threads.  (validated in R5)
// ---------------------------------------------------------------------------
__global__ __launch_bounds__(256) void attn_merge(
    const float* __restrict__ h_dec,
    const float* __restrict__ apart,   // [B][4][PSTRIDE]
    float* __restrict__ out)
{
    const int b   = blockIdx.x;
    const int tid = threadIdx.x;
    const float* base = apart + (size_t)b * 4 * PSTRIDE;

    float mq[4], lq[4];
    #pragma unroll
    for (int q = 0; q < 4; ++q) {
        mq[q] = base[q * PSTRIDE];
        lq[q] = base[q * PSTRIDE + 1];
    }
    const float ms = fmaxf(fmaxf(mq[0], mq[1]), fmaxf(mq[2], mq[3]));
    float L = 0.f;
    float fq[4];
    #pragma unroll
    for (int q = 0; q < 4; ++q) { fq[q] = __expf(mq[q] - ms); L += lq[q] * fq[q]; }
    const float invL = 1.0f / L;

    const int k = tid * 8;
    fv4 c0 = (fv4)(0.f), c1 = (fv4)(0.f);
    #pragma unroll
    for (int q = 0; q < 4; ++q) {
        const float* a = base + q * PSTRIDE + 8 + k;
        c0 += fq[q] * *(const fv4*)(a);
        c1 += fq[q] * *(const fv4*)(a + 4);
    }
    *(fv4*)&out[(size_t)b * DD + k]     = c0 * invL;
    *(fv4*)&out[(size_t)b * DD + k + 4] = c1 * invL;

    // append h_dec as row TC of new_prev
    const float* hp = h_dec + (size_t)b * DD + k;
    float* op = out + (size_t)BB * DD + ((size_t)b * (TCC + 1) + TCC) * DD + k;
    *(fv4*)op       = *(const fv4*)hp;
    *(fv4*)(op + 4) = *(const fv4*)(hp + 4);
}

extern "C" void kernel_launch(void* const* d_in, const int* in_sizes, int n_in,
                              void* d_out, int out_size, void* d_ws, size_t ws_size,
                              hipStream_t stream) {
    const float* h_dec = (const float*)d_in[0];
    const float* prev  = (const float*)d_in[1];
    const unsigned char* maskb = (const unsigned char*)d_in[2];
    const float* W = (const float*)d_in[3];
    float* out   = (float*)d_out;
    float* part  = (float*)d_ws;                       // 8 MB gemm partials
    float* apart = part + (size_t)4 * BB * DD;         // 8.4 MB attn partials

    hipLaunchKernelGGL(hw_gemm_partial, dim3(32, 4, 4), dim3(256), 0, stream,
                       h_dec, W, part);
    hipLaunchKernelGGL(attn_part6, dim3(4, BB), dim3(256), 0, stream,
                       prev, maskb, part, apart, out);
    hipLaunchKernelGGL(attn_merge, dim3(BB), dim3(256), 0, stream,
                       h_dec, apart, out);
}

// Round 8
// 265.158 us; speedup vs baseline: 1.0489x; 1.0489x over previous
//
#include <hip/hip_runtime.h>
#include <math.h>

#define BB  256
#define TCC 256
#define DD  2048
#define GZ  8      // GEMM K-splits

typedef float4 f4;
typedef float __attribute__((ext_vector_type(4))) fv4;

// ---------------------------------------------------------------------------
// Kernel A v2: hw = h_dec @ W (f32), split-K into 8 partials in d_ws.
// grid (16 e-tiles, 2 b-tiles, 8 k-splits), 256 threads, tile 128e x 128b,
// micro-tile 8x8 per thread as 2+2 four-float fragments (ie*4 / 64+ie*4 ->
// contiguous 64-float span per 16 lanes = 2-way LDS aliasing = free).
// LDS bytes/FLOP cut 4x vs the old 4x4 micro-tile (was ~41 us LDS-bound).
// ---------------------------------------------------------------------------
__global__ __launch_bounds__(256) void hw_gemm_partial(
    const float* __restrict__ h,     // [B][D]
    const float* __restrict__ W,     // [D][D]
    float* __restrict__ part)        // [GZ][B][D]
{
    __shared__ float hs[32][136];    // [d][b] transposed, padded
    __shared__ float wsm[32][128];   // [d][e]

    const int tid = threadIdx.x;
    const int e0 = blockIdx.x * 128;
    const int b0 = blockIdx.y * 128;
    const int z  = blockIdx.z;

    float acc[8][8];
    #pragma unroll
    for (int i = 0; i < 8; i++)
        #pragma unroll
        for (int j = 0; j < 8; j++) acc[i][j] = 0.f;

    const int ie = tid & 15;         // e fragment group
    const int ib = tid >> 4;         // b fragment group

    const int hr = tid >> 1;         // 0..127 : b row for h staging
    const int hc = (tid & 1) * 16;   // d offset (0 or 16)
    const int wr = tid >> 3;         // 0..31 : d row for W staging
    const int wc = (tid & 7) * 16;   // e offset

    for (int d0 = z * 256; d0 < z * 256 + 256; d0 += 32) {
        // stage h transposed: hs[d][b], 16 floats per thread
        {
            const float* hp = &h[(size_t)(b0 + hr) * DD + d0 + hc];
            f4 h0 = *(const f4*)(hp);
            f4 h1 = *(const f4*)(hp + 4);
            f4 h2 = *(const f4*)(hp + 8);
            f4 h3 = *(const f4*)(hp + 12);
            hs[hc + 0][hr] = h0.x;  hs[hc + 1][hr] = h0.y;
            hs[hc + 2][hr] = h0.z;  hs[hc + 3][hr] = h0.w;
            hs[hc + 4][hr] = h1.x;  hs[hc + 5][hr] = h1.y;
            hs[hc + 6][hr] = h1.z;  hs[hc + 7][hr] = h1.w;
            hs[hc + 8][hr] = h2.x;  hs[hc + 9][hr] = h2.y;
            hs[hc + 10][hr] = h2.z; hs[hc + 11][hr] = h2.w;
            hs[hc + 12][hr] = h3.x; hs[hc + 13][hr] = h3.y;
            hs[hc + 14][hr] = h3.z; hs[hc + 15][hr] = h3.w;
        }
        // stage W: wsm[d][e], 16 floats per thread
        {
            const float* wp = &W[(size_t)(d0 + wr) * DD + e0 + wc];
            *(f4*)&wsm[wr][wc]      = *(const f4*)(wp);
            *(f4*)&wsm[wr][wc + 4]  = *(const f4*)(wp + 4);
            *(f4*)&wsm[wr][wc + 8]  = *(const f4*)(wp + 8);
            *(f4*)&wsm[wr][wc + 12] = *(const f4*)(wp + 12);
        }
        __syncthreads();

        #pragma unroll
        for (int dd = 0; dd < 32; dd++) {
            fv4 ev0 = *(const fv4*)&wsm[dd][ie * 4];
            fv4 ev1 = *(const fv4*)&wsm[dd][64 + ie * 4];
            fv4 bv0 = *(const fv4*)&hs[dd][ib * 4];
            fv4 bv1 = *(const fv4*)&hs[dd][64 + ib * 4];
            float bb[8] = {bv0.x, bv0.y, bv0.z, bv0.w, bv1.x, bv1.y, bv1.z, bv1.w};
            float ee[8] = {ev0.x, ev0.y, ev0.z, ev0.w, ev1.x, ev1.y, ev1.z, ev1.w};
            #pragma unroll
            for (int i = 0; i < 8; i++)
                #pragma unroll
                for (int j = 0; j < 8; j++)
                    acc[i][j] += bb[i] * ee[j];
        }
        __syncthreads();
    }

    #pragma unroll
    for (int i = 0; i < 8; i++) {
        const int row = b0 + ((i < 4) ? (ib * 4 + i) : (64 + ib * 4 + i - 4));
        float* pr = &part[((size_t)z * BB + row) * DD + e0];
        f4 v0 = make_float4(acc[i][0], acc[i][1], acc[i][2], acc[i][3]);
        f4 v1 = make_float4(acc[i][4], acc[i][5], acc[i][6], acc[i][7]);
        *(f4*)&pr[ie * 4]      = v0;
        *(f4*)&pr[64 + ie * 4] = v1;
    }
}

// ---------------------------------------------------------------------------
// Kernel B: EXACT revert to R1's v1 (measured best attn: plain cached
// loads/stores, next-row register prefetch, lockstep 4-group online
// softmax), with only the split-K partial reduction widened to GZ=8.
// One block per b, 1024 threads = 4 groups x 256.
// ---------------------------------------------------------------------------
__global__ __launch_bounds__(1024) void attn_fused(
    const float* __restrict__ h_dec,   // [B][D]
    const float* __restrict__ prev,    // [B][TC][D]
    const unsigned char* __restrict__ maskb,
    const float* __restrict__ part,    // [GZ][B][D] hw partials
    float* __restrict__ out)           // [B*D ctx | B*(TC+1)*D new_prev]
{
    __shared__ float hw[DD];           // hw row; reused as ctx at the end
    __shared__ float wred[2][16];
    __shared__ float gm[4], gl[4];

    const int b   = blockIdx.x;
    const int tid = threadIdx.x;

    // reduce the GZ split-K partials -> hw row in LDS
    for (int k = tid; k < DD; k += 1024) {
        float s = 0.f;
        #pragma unroll
        for (int z = 0; z < GZ; ++z)
            s += part[((size_t)z * BB + b) * DD + k];
        hw[k] = s;
    }

    // mask dtype-layout detection: bool bytes -> nonzero bytes at k%4!=0
    int nz = 0;
    #pragma unroll
    for (int k = 1; k < 64; k++)
        if ((k & 3) != 0) nz += (maskb[k] != 0);
    const bool boolLayout = (nz > 0);
    const int* maski = (const int*)maskb;

    __syncthreads();

    const int g    = tid >> 8;       // group 0..3
    const int tl   = tid & 255;      // thread-in-group
    const int wv   = tid >> 6;       // wave 0..15
    const int lane = tid & 63;

    float hwr[8];
    #pragma unroll
    for (int j = 0; j < 8; j++) hwr[j] = hw[tl * 8 + j];

    float m = -INFINITY, l = 0.f;
    float acc[8] = {0.f, 0.f, 0.f, 0.f, 0.f, 0.f, 0.f, 0.f};

    const float* pb = prev + (size_t)b * TCC * DD + tl * 8;
    float* cp = out + (size_t)BB * DD + (size_t)b * (TCC + 1) * DD + tl * 8;

    f4 c0 = *(const f4*)(pb + (size_t)(g * 64) * DD);
    f4 c1 = *(const f4*)(pb + (size_t)(g * 64) * DD + 4);

    for (int i = 0; i < 64; i++) {
        const int t = g * 64 + i;
        f4 n0 = c0, n1 = c1;
        if (i < 63) {
            n0 = *(const f4*)(pb + (size_t)(t + 1) * DD);
            n1 = *(const f4*)(pb + (size_t)(t + 1) * DD + 4);
        }
        // fused copy into new_prev
        *(f4*)(cp + (size_t)t * DD)     = c0;
        *(f4*)(cp + (size_t)t * DD + 4) = c1;
        // partial dot with hw row (registers)
        float p = c0.x * hwr[0] + c0.y * hwr[1] + c0.z * hwr[2] + c0.w * hwr[3]
                + c1.x * hwr[4] + c1.y * hwr[5] + c1.z * hwr[6] + c1.w * hwr[7];
        #pragma unroll
        for (int off = 32; off; off >>= 1) p += __shfl_xor(p, off, 64);
        if (lane == 0) wred[i & 1][wv] = p;
        __syncthreads();
        const float e = wred[i & 1][4 * g] + wred[i & 1][4 * g + 1]
                      + wred[i & 1][4 * g + 2] + wred[i & 1][4 * g + 3];
        const bool mk = boolLayout ? (maskb[(size_t)b * TCC + t] != 0)
                                   : (maski[(size_t)b * TCC + t] != 0);
        if (mk) {
            if (e > m) {
                const float sc = __expf(m - e);   // m=-inf first time -> 0
                l *= sc;
                #pragma unroll
                for (int j = 0; j < 8; j++) acc[j] *= sc;
                m = e;
            }
            const float w = __expf(e - m);
            l += w;
            acc[0] += w * c0.x; acc[1] += w * c0.y;
            acc[2] += w * c0.z; acc[3] += w * c0.w;
            acc[4] += w * c1.x; acc[5] += w * c1.y;
            acc[6] += w * c1.z; acc[7] += w * c1.w;
        }
        c0 = n0; c1 = n1;
    }

    // merge the 4 groups (flash-style)
    __syncthreads();
    if (tl == 0) { gm[g] = m; gl[g] = l; }
    __syncthreads();
    const float mstar = fmaxf(fmaxf(gm[0], gm[1]), fmaxf(gm[2], gm[3]));
    float L = 0.f;
    #pragma unroll
    for (int q = 0; q < 4; q++) L += gl[q] * __expf(gm[q] - mstar);
    const float f = __expf(gm[g] - mstar);

    for (int ph = 0; ph < 4; ph++) {
        if (g == ph) {
            #pragma unroll
            for (int j = 0; j < 8; j++) {
                if (ph == 0) hw[tl * 8 + j]  = f * acc[j];
                else         hw[tl * 8 + j] += f * acc[j];
            }
        }
        __syncthreads();
    }

    const float invL = 1.0f / L;
    for (int k = tid; k < DD; k += 1024)
        out[(size_t)b * DD + k] = hw[k] * invL;
    // append h_dec as row TC of new_prev
    for (int k = tid; k < DD; k += 1024)
        out[(size_t)BB * DD + ((size_t)b * (TCC + 1) + TCC) * DD + k] =
            h_dec[(size_t)b * DD + k];
}

extern "C" void kernel_launch(void* const* d_in, const int* in_sizes, int n_in,
                              void* d_out, int out_size, void* d_ws, size_t ws_size,
                              hipStream_t stream) {
    const float* h_dec = (const float*)d_in[0];
    const float* prev  = (const float*)d_in[1];
    const unsigned char* maskb = (const unsigned char*)d_in[2];
    const float* W = (const float*)d_in[3];
    float* out  = (float*)d_out;
    float* part = (float*)d_ws;   // GZ * B * D * 4 = 16 MB of scratch

    hipLaunchKernelGGL(hw_gemm_partial, dim3(16, 2, GZ), dim3(256), 0, stream,
                       h_dec, W, part);
    hipLaunchKernelGGL(attn_fused, dim3(BB), dim3(1024), 0, stream,
                       h_dec, prev, maskb, part, out);
}